// Round 7
// baseline (3928.609 us; speedup 1.0000x reference)
//
#include <hip/hip_runtime.h>
#include <hip/hip_bf16.h>

#define SEQ_LEN 256
#define HIDDEN  2048
#define CLASSES 10
#define BATCH   128
#define NWG     256
#define WG_THREADS 512
#define STEPS   (SEQ_LEN - 1)
#define KTILES  64            // 2048 / 32
#define PF      16            // A-prefetch depth; also reg-B tail length
#define LDS_WH  131072
#define LDS_ALL (LDS_WH + 4096)

typedef __attribute__((ext_vector_type(8))) short  bf16x8;
typedef __attribute__((ext_vector_type(8))) unsigned short u16x8;
typedef __attribute__((ext_vector_type(4))) float  f32x4;
typedef __attribute__((ext_vector_type(4))) unsigned int u32x4;

// ---- workspace layout (bytes) ----
#define WHP_OFF  0
#define HB_OFF   33554432UL                    // 4 x 512 KB rotating h buffers, layout h[cb][row][u]
#define HF_OFF   (HB_OFF + 4UL * 524288UL)     // fp32 h_final [128][2048]
#define BAR_OFF  (HF_OFF + 1048576UL)
// bar layout (dwords):
//   [0..255]          arrival slot per WG (posted stores; leader L polls [32L..32L+32))
//   [512 + 16*L]      done[L], L=0..7 (64B apart)
//   [1024 + 16*j]     release line j, j=0..31 (64B apart; WG polls j = W & 31)
// Session lessons: R2 flat all-poll barrier = coherence-point contention
// (+2.8us/step) — keep the contention-free tree. R4: don't restructure the
// MFMA acc chain (schedule perturbation costs more than ILP gains). R5:
// agent-scope partial exchange = HBM write-through with 8x partial-line
// amplification; only lane-contiguous posted stores merge into full lines.
// R6: consumption is all-to-all per step, so fine-grained producer flags
// cannot beat the barrier on the critical path — they only add VALU overhead.
// R7: cut pipe-work instead: (a) no redundant tail-clamp prefetches (25% of
// TA traffic was clamped L1 re-hits), (b) last-16-ktile B-fragments live in
// registers across the whole t-loop (25% of LDS read traffic removed).

__device__ __forceinline__ unsigned short f2bf(float f) {
    unsigned int u = __float_as_uint(f);
    return (unsigned short)((u + 0x7FFFu + ((u >> 16) & 1u)) >> 16);
}
__device__ __forceinline__ float sigm(float z)  { return 1.0f / (1.0f + __expf(-z)); }
__device__ __forceinline__ float tanh_f(float z){ return 2.0f / (1.0f + __expf(-2.0f * z)) - 1.0f; }

__device__ __forceinline__ unsigned int aload(const unsigned int* p) {
    return __hip_atomic_load(p, __ATOMIC_RELAXED, __HIP_MEMORY_SCOPE_AGENT);
}
__device__ __forceinline__ void astore(unsigned int* p, unsigned int v) {
    __hip_atomic_store(p, v, __ATOMIC_RELAXED, __HIP_MEMORY_SCOPE_AGENT);
}

// Pack Wh [2048][8192] fp32 -> bf16 in exact MFMA B-fragment order (R1 layout).
__global__ void lstm_pack_kernel(const float* __restrict__ Wh,
                                 unsigned short* __restrict__ whp,
                                 unsigned short* __restrict__ hbufs,
                                 unsigned int* __restrict__ bar) {
    int chunk = blockIdx.x * 256 + threadIdx.x;     // 2,097,152 chunks total
    int lane = chunk & 63;
    int nt   = (chunk >> 6) & 1;
    int kt   = (chunk >> 7) & 63;
    int W    = chunk >> 13;
    int q = lane >> 4, l16 = lane & 15;
    int c32  = nt * 16 + l16;
    int gate = c32 >> 3, u = c32 & 7;
    int n    = gate * 2048 + W * 8 + u;
    int k0   = kt * 32 + q * 8;
    u16x8 frag;
    #pragma unroll
    for (int j = 0; j < 8; ++j)
        frag[j] = f2bf(Wh[(size_t)(k0 + j) * 8192 + n]);
    ((u16x8*)whp)[chunk] = frag;

    if (chunk < 32768) ((u32x4*)hbufs)[chunk] = (u32x4){0, 0, 0, 0};   // buf0: h(0)=0
    if (chunk < 2048) bar[chunk] = 0u;                                 // barrier words
}

// Contention-free monotonic tree barrier (phase = t+1, never reset).
// h stores are posted agent-scope; the leading __syncthreads drains them
// before the arrival store -> release ordering. Acquire inv only when do_inv.
__device__ __forceinline__ void grid_barrier(unsigned int* bar, unsigned int phase,
                                             bool do_inv, int W) {
    __syncthreads();   // drain h stores to the coherence point
    if (threadIdx.x < 64) {
        const int lane = threadIdx.x;
        if (lane == 0) astore(&bar[W], phase);                 // arrival
        if (W < 8) {
            unsigned int* sl = &bar[W * 32 + (lane & 31)];
            while (!__all((int)(aload(sl) >= phase)))
                __builtin_amdgcn_s_sleep(1);
            if (lane == 0) astore(&bar[512 + 16 * W], phase);  // done[W]
            if (W == 0) {
                unsigned int* dn = &bar[512 + 16 * (lane & 7)];
                while (!__all((int)(aload(dn) >= phase)))
                    __builtin_amdgcn_s_sleep(1);
                if (lane < 32) astore(&bar[1024 + 16 * lane], phase);  // broadcast
            }
        }
        if (lane == 0 && W != 0) {
            unsigned int* rl = &bar[1024 + 16 * (W & 31)];
            while (aload(rl) < phase)
                __builtin_amdgcn_s_sleep(1);
        }
        if (do_inv)
            __builtin_amdgcn_fence(__ATOMIC_ACQUIRE, "agent");   // buffer_inv (L1+L2)
    }
    __syncthreads();
}

__global__ __launch_bounds__(WG_THREADS, 2) void lstm_persist(
    const float* __restrict__ x,  const float* __restrict__ Wx,
    const float* __restrict__ b,  const float* __restrict__ Wph,
    const float* __restrict__ bp, const unsigned short* __restrict__ whp,
    unsigned short* hbufs, float* hfin,
    unsigned int* bar, float* out)
{
    extern __shared__ char lds[];
    const int tid = threadIdx.x;
    const int W   = blockIdx.x;

    // stage this WG's Wh slice (128 KB) into LDS
    {
        const u32x4* src = (const u32x4*)whp + (size_t)W * 8192;
        u32x4* dst = (u32x4*)lds;
        for (int i = tid; i < 8192; i += WG_THREADS) dst[i] = src[i];
    }
    unsigned short* hstage = (unsigned short*)(lds + LDS_WH);   // [row][u] bf16, 2 KB
    __syncthreads();

    const int lane = tid & 63;
    const int wv   = tid >> 6;          // wave 0..7 -> M-tile
    const int q    = lane >> 4;         // quad 0..3
    const int l16  = lane & 15;
    const int s    = (lane >> 3) & 1;   // 0: holds (g,f); 1: holds (i,o)
    const int u    = lane & 7;          // hidden unit within slice
    const int rowA = wv * 16 + l16;     // A row this lane loads
    const int row0 = wv * 16 + q * 4;   // C/D rows row0..row0+3
    const int colh = W * 8 + u;         // global hidden index this lane updates

    const int n0 = ((l16) >> 3) * 2048 + W * 8 + (l16 & 7);
    const int n1 = ((16 + l16) >> 3) * 2048 + W * 8 + ((16 + l16) & 7);
    const float wx0 = Wx[n0], bb0 = b[n0];
    const float wx1 = Wx[n1], bb1 = b[n1];

    // A-fragment address in the blocked layout h[cb][row][u]:
    // lane (q,row) reads h[kt*4+q][rowA][0..7] = one contiguous bf16x8 at
    // index (kt*4+q)*128+rowA; a quad's 16 lanes span 256 B contiguous.
    const int abase = q * 128 + rowA;

    // B-fragments for ktiles 48..63 are constant across all 255 steps:
    // hold them in registers for the whole t-loop (32 frags = 128 VGPR).
    // Removes 25% of the per-step LDS read traffic.
    bf16x8 breg[2 * PF];
    {
        const char* lp0 = lds + lane * 16;
        #pragma unroll
        for (int i = 0; i < PF; ++i) {
            breg[2 * i]     = *(const bf16x8*)(lp0 + (((KTILES - PF) + i) * 2 + 0) * 1024);
            breg[2 * i + 1] = *(const bf16x8*)(lp0 + (((KTILES - PF) + i) * 2 + 1) * 1024);
        }
    }

    float c_state[4] = {0.f, 0.f, 0.f, 0.f};

    for (int t = 0; t < STEPS; ++t) {
        unsigned short* hcur  = hbufs + (size_t)(t & 3) * 262144;        // elements
        unsigned short* hnext = hbufs + (size_t)((t + 1) & 3) * 262144;

        const bf16x8* hc8 = (const bf16x8*)hcur;
        const char* lp = lds + lane * 16;

        float xv[4];
        #pragma unroll
        for (int r = 0; r < 4; ++r) xv[r] = x[(row0 + r) * SEQ_LEN + t];

        // 16-deep rotating register prefetch of A fragments, PF ktiles ahead.
        bf16x8 a_pf[PF];
        #pragma unroll
        for (int i = 0; i < PF; ++i)
            a_pf[i] = hc8[abase + i * 512];

        f32x4 acc0 = {0.f, 0.f, 0.f, 0.f};
        f32x4 acc1 = {0.f, 0.f, 0.f, 0.f};
        // phase A (kt 0..47): prefetch kt+16 is always in range -> no clamp,
        // no redundant tail loads (they were 25% of the TA traffic in R1).
        #pragma unroll 16
        for (int kt = 0; kt < KTILES - PF; ++kt) {
            bf16x8 a_cur = a_pf[kt & (PF - 1)];       // static idx under unroll-16
            a_pf[kt & (PF - 1)] = hc8[abase + (kt + PF) * 512];
            bf16x8 b0 = *(const bf16x8*)(lp + (kt * 2 + 0) * 1024);
            bf16x8 b1 = *(const bf16x8*)(lp + (kt * 2 + 1) * 1024);
            acc0 = __builtin_amdgcn_mfma_f32_16x16x32_bf16(a_cur, b0, acc0, 0, 0, 0);
            acc1 = __builtin_amdgcn_mfma_f32_16x16x32_bf16(a_cur, b1, acc1, 0, 0, 0);
        }
        // phase B (kt 48..63): pure-MFMA burst, A from a_pf, B from registers.
        #pragma unroll
        for (int i = 0; i < PF; ++i) {
            bf16x8 a_cur = a_pf[i];
            acc0 = __builtin_amdgcn_mfma_f32_16x16x32_bf16(a_cur, breg[2 * i],     acc0, 0, 0, 0);
            acc1 = __builtin_amdgcn_mfma_f32_16x16x32_bf16(a_cur, breg[2 * i + 1], acc1, 0, 0, 0);
        }

        const bool last = (t == STEPS - 1);
        #pragma unroll
        for (int r = 0; r < 4; ++r) {
            float z0 = acc0[r] + xv[r] * wx0 + bb0;
            float z1 = acc1[r] + xv[r] * wx1 + bb1;
            float p0 = __shfl_xor(z0, 8, 64);
            float p1 = __shfl_xor(z1, 8, 64);
            float zg = s ? p0 : z0;
            float zi = s ? z0 : p0;
            float zf = s ? p1 : z1;
            float zo = s ? z1 : p1;
            float cn = tanh_f(zg) * sigm(zi) + c_state[r] * sigm(zf);
            c_state[r] = cn;
            float h = tanh_f(cn) * sigm(zo);
            if (s == 0) {
                hstage[(row0 + r) * 8 + u] = f2bf(h);      // stage into LDS
                if (last)
                    __hip_atomic_store(&hfin[(row0 + r) * HIDDEN + colh], h,
                                       __ATOMIC_RELAXED, __HIP_MEMORY_SCOPE_AGENT);
            }
        }
        __syncthreads();   // hstage complete
        // cooperative coalesced write of this WG's 2 KB h-block (1 dword/thread;
        // lane-contiguous posted stores -> full-line write-through)
        astore(&((unsigned int*)hnext)[W * 512 + tid],
               ((const unsigned int*)hstage)[tid]);
        // inv every 4th barrier (stale L2 age <= 4 with the 4-buffer rotation);
        // t==254 (phase 2) also covers the hfin handoff to the cached epilogue.
        grid_barrier(bar, (unsigned int)(t + 1), (t & 3) == 2 || last, W);
    }

    // ---- classifier + softmax epilogue: WG b handles batch row b ----
    if (W < BATCH) {
        float part[CLASSES];
        #pragma unroll
        for (int c = 0; c < CLASSES; ++c) part[c] = 0.f;
        for (int k = tid; k < HIDDEN; k += WG_THREADS) {
            float hv = hfin[W * HIDDEN + k];
            #pragma unroll
            for (int c = 0; c < CLASSES; ++c) part[c] += hv * Wph[k * CLASSES + c];
        }
        #pragma unroll
        for (int c = 0; c < CLASSES; ++c)
            for (int off = 32; off > 0; off >>= 1)
                part[c] += __shfl_xor(part[c], off, 64);
        float* red = (float*)(lds + LDS_WH);
        __syncthreads();
        if (lane == 0)
            for (int c = 0; c < CLASSES; ++c) red[wv * CLASSES + c] = part[c];
        __syncthreads();
        if (tid == 0) {
            float lg[CLASSES];
            for (int c = 0; c < CLASSES; ++c) {
                float sm = bp[c];
                for (int w8 = 0; w8 < 8; ++w8) sm += red[w8 * CLASSES + c];
                lg[c] = sm;
            }
            float mx = lg[0];
            for (int c = 1; c < CLASSES; ++c) mx = fmaxf(mx, lg[c]);
            float se = 0.f;
            for (int c = 0; c < CLASSES; ++c) { lg[c] = __expf(lg[c] - mx); se += lg[c]; }
            float inv = 1.0f / se;
            for (int c = 0; c < CLASSES; ++c) out[W * CLASSES + c] = lg[c] * inv;
        }
    }
}

extern "C" void kernel_launch(void* const* d_in, const int* in_sizes, int n_in,
                              void* d_out, int out_size, void* d_ws, size_t ws_size,
                              hipStream_t stream) {
    const float* x   = (const float*)d_in[0];
    const float* Wx  = (const float*)d_in[1];
    const float* Wh  = (const float*)d_in[2];
    const float* b   = (const float*)d_in[3];
    const float* Wph = (const float*)d_in[4];
    const float* bp  = (const float*)d_in[5];
    float* out = (float*)d_out;

    char* ws = (char*)d_ws;
    unsigned short* whp  = (unsigned short*)(ws + WHP_OFF);
    unsigned short* hbufs= (unsigned short*)(ws + HB_OFF);
    float*          hfin = (float*)(ws + HF_OFF);
    unsigned int*   bar  = (unsigned int*)(ws + BAR_OFF);

    hipFuncSetAttribute((const void*)lstm_persist,
                        hipFuncAttributeMaxDynamicSharedMemorySize, LDS_ALL);

    lstm_pack_kernel<<<8192, 256, 0, stream>>>(Wh, whp, hbufs, bar);
    lstm_persist<<<NWG, WG_THREADS, LDS_ALL, stream>>>(x, Wx, b, Wph, bp,
                                                       whp, hbufs, hfin, bar, out);
}

// Round 8
// 2613.306 us; speedup vs baseline: 1.5033x; 1.5033x over previous
//
#include <hip/hip_runtime.h>
#include <hip/hip_bf16.h>

#define SEQ_LEN 256
#define HIDDEN  2048
#define CLASSES 10
#define BATCH   128
#define NWG     256
#define WG_THREADS 512
#define STEPS   (SEQ_LEN - 1)
#define KTILES  64            // 2048 / 32
#define PF      16            // A-prefetch depth (ktiles ahead)
#define LDS_WH  131072
#define LDS_ALL (LDS_WH + 4096)

typedef __attribute__((ext_vector_type(8))) short  bf16x8;
typedef __attribute__((ext_vector_type(8))) unsigned short u16x8;
typedef __attribute__((ext_vector_type(4))) float  f32x4;
typedef __attribute__((ext_vector_type(4))) unsigned int u32x4;

// ---- workspace layout (bytes) ----
#define WHP_OFF  0
#define HB_OFF   33554432UL                    // 4 x 512 KB rotating h buffers, layout h[cb][row][u]
#define HF_OFF   (HB_OFF + 4UL * 524288UL)     // fp32 h_final [128][2048]
#define BAR_OFF  (HF_OFF + 1048576UL)
// bar layout (dwords):
//   [0..255]          arrival slot per WG (posted stores; leader L polls [32L..32L+32))
//   [512 + 16*L]      done[L], L=0..7 (64B apart)
//   [1024 + 16*j]     release line j, j=0..31 (64B apart; WG polls j = W & 31)
// Session lessons: R2 flat all-poll barrier = coherence-point contention
// (+2.8us/step) — keep the contention-free tree. R4: don't restructure the
// MFMA acc chain. R5: agent-scope partial exchange = HBM write-through with
// 8x partial-line amplification (only lane-contiguous posted stores merge).
// R6: consumption is all-to-all per step -> producer flags can't beat the
// barrier, they only add VALU. R7: breg (128 VGPR) blew the 256-VGPR budget
// -> scratch spills (FETCH 541MB->2.1GB). This round: tail-split ONLY —
// register-neutral removal of the clamp + 16 redundant prefetches/wave/step.

__device__ __forceinline__ unsigned short f2bf(float f) {
    unsigned int u = __float_as_uint(f);
    return (unsigned short)((u + 0x7FFFu + ((u >> 16) & 1u)) >> 16);
}
__device__ __forceinline__ float sigm(float z)  { return 1.0f / (1.0f + __expf(-z)); }
__device__ __forceinline__ float tanh_f(float z){ return 2.0f / (1.0f + __expf(-2.0f * z)) - 1.0f; }

__device__ __forceinline__ unsigned int aload(const unsigned int* p) {
    return __hip_atomic_load(p, __ATOMIC_RELAXED, __HIP_MEMORY_SCOPE_AGENT);
}
__device__ __forceinline__ void astore(unsigned int* p, unsigned int v) {
    __hip_atomic_store(p, v, __ATOMIC_RELAXED, __HIP_MEMORY_SCOPE_AGENT);
}

// Pack Wh [2048][8192] fp32 -> bf16 in exact MFMA B-fragment order (R1 layout).
__global__ void lstm_pack_kernel(const float* __restrict__ Wh,
                                 unsigned short* __restrict__ whp,
                                 unsigned short* __restrict__ hbufs,
                                 unsigned int* __restrict__ bar) {
    int chunk = blockIdx.x * 256 + threadIdx.x;     // 2,097,152 chunks total
    int lane = chunk & 63;
    int nt   = (chunk >> 6) & 1;
    int kt   = (chunk >> 7) & 63;
    int W    = chunk >> 13;
    int q = lane >> 4, l16 = lane & 15;
    int c32  = nt * 16 + l16;
    int gate = c32 >> 3, u = c32 & 7;
    int n    = gate * 2048 + W * 8 + u;
    int k0   = kt * 32 + q * 8;
    u16x8 frag;
    #pragma unroll
    for (int j = 0; j < 8; ++j)
        frag[j] = f2bf(Wh[(size_t)(k0 + j) * 8192 + n]);
    ((u16x8*)whp)[chunk] = frag;

    if (chunk < 32768) ((u32x4*)hbufs)[chunk] = (u32x4){0, 0, 0, 0};   // buf0: h(0)=0
    if (chunk < 2048) bar[chunk] = 0u;                                 // barrier words
}

// Contention-free monotonic tree barrier (phase = t+1, never reset).
// h stores are posted agent-scope; the leading __syncthreads drains them
// before the arrival store -> release ordering. Acquire inv only when do_inv.
__device__ __forceinline__ void grid_barrier(unsigned int* bar, unsigned int phase,
                                             bool do_inv, int W) {
    __syncthreads();   // drain h stores to the coherence point
    if (threadIdx.x < 64) {
        const int lane = threadIdx.x;
        if (lane == 0) astore(&bar[W], phase);                 // arrival
        if (W < 8) {
            unsigned int* sl = &bar[W * 32 + (lane & 31)];
            while (!__all((int)(aload(sl) >= phase)))
                __builtin_amdgcn_s_sleep(1);
            if (lane == 0) astore(&bar[512 + 16 * W], phase);  // done[W]
            if (W == 0) {
                unsigned int* dn = &bar[512 + 16 * (lane & 7)];
                while (!__all((int)(aload(dn) >= phase)))
                    __builtin_amdgcn_s_sleep(1);
                if (lane < 32) astore(&bar[1024 + 16 * lane], phase);  // broadcast
            }
        }
        if (lane == 0 && W != 0) {
            unsigned int* rl = &bar[1024 + 16 * (W & 31)];
            while (aload(rl) < phase)
                __builtin_amdgcn_s_sleep(1);
        }
        if (do_inv)
            __builtin_amdgcn_fence(__ATOMIC_ACQUIRE, "agent");   // buffer_inv (L1+L2)
    }
    __syncthreads();
}

__global__ __launch_bounds__(WG_THREADS, 2) void lstm_persist(
    const float* __restrict__ x,  const float* __restrict__ Wx,
    const float* __restrict__ b,  const float* __restrict__ Wph,
    const float* __restrict__ bp, const unsigned short* __restrict__ whp,
    unsigned short* hbufs, float* hfin,
    unsigned int* bar, float* out)
{
    extern __shared__ char lds[];
    const int tid = threadIdx.x;
    const int W   = blockIdx.x;

    // stage this WG's Wh slice (128 KB) into LDS
    {
        const u32x4* src = (const u32x4*)whp + (size_t)W * 8192;
        u32x4* dst = (u32x4*)lds;
        for (int i = tid; i < 8192; i += WG_THREADS) dst[i] = src[i];
    }
    unsigned short* hstage = (unsigned short*)(lds + LDS_WH);   // [row][u] bf16, 2 KB
    __syncthreads();

    const int lane = tid & 63;
    const int wv   = tid >> 6;          // wave 0..7 -> M-tile
    const int q    = lane >> 4;         // quad 0..3
    const int l16  = lane & 15;
    const int s    = (lane >> 3) & 1;   // 0: holds (g,f); 1: holds (i,o)
    const int u    = lane & 7;          // hidden unit within slice
    const int rowA = wv * 16 + l16;     // A row this lane loads
    const int row0 = wv * 16 + q * 4;   // C/D rows row0..row0+3
    const int colh = W * 8 + u;         // global hidden index this lane updates

    const int n0 = ((l16) >> 3) * 2048 + W * 8 + (l16 & 7);
    const int n1 = ((16 + l16) >> 3) * 2048 + W * 8 + ((16 + l16) & 7);
    const float wx0 = Wx[n0], bb0 = b[n0];
    const float wx1 = Wx[n1], bb1 = b[n1];

    // A-fragment address in the blocked layout h[cb][row][u]:
    // lane (q,row) reads h[kt*4+q][rowA][0..7] = one contiguous bf16x8 at
    // index (kt*4+q)*128+rowA; a quad's 16 lanes span 256 B contiguous.
    const int abase = q * 128 + rowA;

    float c_state[4] = {0.f, 0.f, 0.f, 0.f};

    for (int t = 0; t < STEPS; ++t) {
        unsigned short* hcur  = hbufs + (size_t)(t & 3) * 262144;        // elements
        unsigned short* hnext = hbufs + (size_t)((t + 1) & 3) * 262144;

        const bf16x8* hc8 = (const bf16x8*)hcur;
        const char* lp = lds + lane * 16;

        float xv[4];
        #pragma unroll
        for (int r = 0; r < 4; ++r) xv[r] = x[(row0 + r) * SEQ_LEN + t];

        // 16-deep rotating register prefetch of A fragments, PF ktiles ahead.
        bf16x8 a_pf[PF];
        #pragma unroll
        for (int i = 0; i < PF; ++i)
            a_pf[i] = hc8[abase + i * 512];

        f32x4 acc0 = {0.f, 0.f, 0.f, 0.f};
        f32x4 acc1 = {0.f, 0.f, 0.f, 0.f};
        // phase A (kt 0..47): prefetch kt+PF is always in range -> purely
        // affine prefetch addresses, no clamp select, no redundant tail loads.
        #pragma unroll 16
        for (int kt = 0; kt < KTILES - PF; ++kt) {
            bf16x8 a_cur = a_pf[kt & (PF - 1)];       // static idx under unroll-16
            a_pf[kt & (PF - 1)] = hc8[abase + (kt + PF) * 512];
            bf16x8 b0 = *(const bf16x8*)(lp + (kt * 2 + 0) * 1024);
            bf16x8 b1 = *(const bf16x8*)(lp + (kt * 2 + 1) * 1024);
            acc0 = __builtin_amdgcn_mfma_f32_16x16x32_bf16(a_cur, b0, acc0, 0, 0, 0);
            acc1 = __builtin_amdgcn_mfma_f32_16x16x32_bf16(a_cur, b1, acc1, 0, 0, 0);
        }
        // phase B (kt 48..63): consume a_pf, B from LDS, no prefetch.
        // ((KTILES-PF+i) & (PF-1)) == i, so a_pf[i] is ktile 48+i.
        #pragma unroll
        for (int i = 0; i < PF; ++i) {
            const int kt = (KTILES - PF) + i;
            bf16x8 a_cur = a_pf[i];
            bf16x8 b0 = *(const bf16x8*)(lp + (kt * 2 + 0) * 1024);
            bf16x8 b1 = *(const bf16x8*)(lp + (kt * 2 + 1) * 1024);
            acc0 = __builtin_amdgcn_mfma_f32_16x16x32_bf16(a_cur, b0, acc0, 0, 0, 0);
            acc1 = __builtin_amdgcn_mfma_f32_16x16x32_bf16(a_cur, b1, acc1, 0, 0, 0);
        }

        const bool last = (t == STEPS - 1);
        #pragma unroll
        for (int r = 0; r < 4; ++r) {
            float z0 = acc0[r] + xv[r] * wx0 + bb0;
            float z1 = acc1[r] + xv[r] * wx1 + bb1;
            float p0 = __shfl_xor(z0, 8, 64);
            float p1 = __shfl_xor(z1, 8, 64);
            float zg = s ? p0 : z0;
            float zi = s ? z0 : p0;
            float zf = s ? p1 : z1;
            float zo = s ? z1 : p1;
            float cn = tanh_f(zg) * sigm(zi) + c_state[r] * sigm(zf);
            c_state[r] = cn;
            float h = tanh_f(cn) * sigm(zo);
            if (s == 0) {
                hstage[(row0 + r) * 8 + u] = f2bf(h);      // stage into LDS
                if (last)
                    __hip_atomic_store(&hfin[(row0 + r) * HIDDEN + colh], h,
                                       __ATOMIC_RELAXED, __HIP_MEMORY_SCOPE_AGENT);
            }
        }
        __syncthreads();   // hstage complete
        // cooperative coalesced write of this WG's 2 KB h-block (1 dword/thread;
        // lane-contiguous posted stores -> full-line write-through)
        astore(&((unsigned int*)hnext)[W * 512 + tid],
               ((const unsigned int*)hstage)[tid]);
        // inv every 4th barrier (stale L2 age <= 4 with the 4-buffer rotation);
        // t==254 (phase 2) also covers the hfin handoff to the cached epilogue.
        grid_barrier(bar, (unsigned int)(t + 1), (t & 3) == 2 || last, W);
    }

    // ---- classifier + softmax epilogue: WG b handles batch row b ----
    if (W < BATCH) {
        float part[CLASSES];
        #pragma unroll
        for (int c = 0; c < CLASSES; ++c) part[c] = 0.f;
        for (int k = tid; k < HIDDEN; k += WG_THREADS) {
            float hv = hfin[W * HIDDEN + k];
            #pragma unroll
            for (int c = 0; c < CLASSES; ++c) part[c] += hv * Wph[k * CLASSES + c];
        }
        #pragma unroll
        for (int c = 0; c < CLASSES; ++c)
            for (int off = 32; off > 0; off >>= 1)
                part[c] += __shfl_xor(part[c], off, 64);
        float* red = (float*)(lds + LDS_WH);
        __syncthreads();
        if (lane == 0)
            for (int c = 0; c < CLASSES; ++c) red[wv * CLASSES + c] = part[c];
        __syncthreads();
        if (tid == 0) {
            float lg[CLASSES];
            for (int c = 0; c < CLASSES; ++c) {
                float sm = bp[c];
                for (int w8 = 0; w8 < 8; ++w8) sm += red[w8 * CLASSES + c];
                lg[c] = sm;
            }
            float mx = lg[0];
            for (int c = 1; c < CLASSES; ++c) mx = fmaxf(mx, lg[c]);
            float se = 0.f;
            for (int c = 0; c < CLASSES; ++c) { lg[c] = __expf(lg[c] - mx); se += lg[c]; }
            float inv = 1.0f / se;
            for (int c = 0; c < CLASSES; ++c) out[W * CLASSES + c] = lg[c] * inv;
        }
    }
}

extern "C" void kernel_launch(void* const* d_in, const int* in_sizes, int n_in,
                              void* d_out, int out_size, void* d_ws, size_t ws_size,
                              hipStream_t stream) {
    const float* x   = (const float*)d_in[0];
    const float* Wx  = (const float*)d_in[1];
    const float* Wh  = (const float*)d_in[2];
    const float* b   = (const float*)d_in[3];
    const float* Wph = (const float*)d_in[4];
    const float* bp  = (const float*)d_in[5];
    float* out = (float*)d_out;

    char* ws = (char*)d_ws;
    unsigned short* whp  = (unsigned short*)(ws + WHP_OFF);
    unsigned short* hbufs= (unsigned short*)(ws + HB_OFF);
    float*          hfin = (float*)(ws + HF_OFF);
    unsigned int*   bar  = (unsigned int*)(ws + BAR_OFF);

    hipFuncSetAttribute((const void*)lstm_persist,
                        hipFuncAttributeMaxDynamicSharedMemorySize, LDS_ALL);

    lstm_pack_kernel<<<8192, 256, 0, stream>>>(Wh, whp, hbufs, bar);
    lstm_persist<<<NWG, WG_THREADS, LDS_ALL, stream>>>(x, Wx, b, Wph, bp,
                                                       whp, hbufs, hfin, bar, out);
}

// Round 9
// 2442.057 us; speedup vs baseline: 1.6087x; 1.0701x over previous
//
#include <hip/hip_runtime.h>
#include <hip/hip_bf16.h>

#define SEQ_LEN 256
#define HIDDEN  2048
#define CLASSES 10
#define BATCH   128
#define NWG     256
#define WG_THREADS 512
#define STEPS   (SEQ_LEN - 1)
#define KTILES  64            // per K-half: 1024 / 16
#define PF      16            // A-prefetch depth (ktiles ahead)
#define LDS_WH  131072
#define RED_OFF    LDS_WH                  // K-half reduction: 256 slots * 72 B
#define RED_STRIDE 72
#define HSTAGE_OFF (LDS_WH + 18432)
#define LDS_ALL    (HSTAGE_OFF + 2048)

typedef __attribute__((ext_vector_type(8)))  short  bf16x8;
typedef __attribute__((ext_vector_type(8)))  unsigned short u16x8;
typedef __attribute__((ext_vector_type(16))) float  f32x16;
typedef __attribute__((ext_vector_type(4)))  unsigned int u32x4;

// ---- workspace layout (bytes) ----
#define WHP_OFF  0
#define HB_OFF   33554432UL                    // 4 x 512 KB rotating h buffers, layout h[kblk][row][u]
#define HF_OFF   (HB_OFF + 4UL * 524288UL)     // fp32 h_final [128][2048]
#define BAR_OFF  (HF_OFF + 1048576UL)
// bar layout (dwords): as R1 (contention-free tree, monotonic phases).
// Session lessons: R2 flat all-poll barrier = coherence-point contention.
// R4: don't perturb the MFMA/load schedule for ILP. R5: agent-scope partial
// exchange = HBM write-through + 8x partial-line amplification (exchange must
// go through LDS). R6: all-to-all consumption -> flags can't beat the barrier.
// R7: 128-VGPR breg = spills. R8: tail-split (no clamp, no redundant tail
// prefetch) is a real ~4% win.
// R9: the binding pipe is LDS B-reads (8 waves read IDENTICAL b-fragments:
// 1 MB/step/CU ~ 5.1us at 85 B/cyc). 32x32x16 MFMA + in-CU K-split halves
// that (4x redundancy, 512 KB/step); K-halves reduce through LDS (18 KB,
// stride-72 slots ~4-way conflicts only). A-traffic, h layout, h-write,
// barrier, inv cadence byte-identical to R1/R8.

__device__ __forceinline__ unsigned short f2bf(float f) {
    unsigned int u = __float_as_uint(f);
    return (unsigned short)((u + 0x7FFFu + ((u >> 16) & 1u)) >> 16);
}
__device__ __forceinline__ float sigm(float z)  { return 1.0f / (1.0f + __expf(-z)); }
__device__ __forceinline__ float tanh_f(float z){ return 2.0f / (1.0f + __expf(-2.0f * z)) - 1.0f; }

__device__ __forceinline__ unsigned int aload(const unsigned int* p) {
    return __hip_atomic_load(p, __ATOMIC_RELAXED, __HIP_MEMORY_SCOPE_AGENT);
}
__device__ __forceinline__ void astore(unsigned int* p, unsigned int v) {
    __hip_atomic_store(p, v, __ATOMIC_RELAXED, __HIP_MEMORY_SCOPE_AGENT);
}

// Pack Wh [2048][8192] fp32 -> bf16 32x32x16 B-fragments.
// whp chunk = W*8192 + kh*4096 + kt*64 + lane (16 B units).
// Fragment: col = lane&31 -> (gate = col>>3, u = col&7), k = kh*1024 + kt*16
// + (lane>>5)*8 + j.  (k-octet convention cancels between A and B.)
__global__ void lstm_pack_kernel(const float* __restrict__ Wh,
                                 unsigned short* __restrict__ whp,
                                 unsigned short* __restrict__ hbufs,
                                 unsigned int* __restrict__ bar) {
    int chunk = blockIdx.x * 256 + threadIdx.x;     // 2,097,152 chunks total
    int lane = chunk & 63;
    int kt   = (chunk >> 6) & 63;
    int kh   = (chunk >> 12) & 1;
    int W    = chunk >> 13;
    int c    = lane & 31;
    int oct  = lane >> 5;
    int gate = c >> 3, u = c & 7;
    int n    = gate * 2048 + W * 8 + u;
    int k0   = kh * 1024 + kt * 16 + oct * 8;
    u16x8 frag;
    #pragma unroll
    for (int j = 0; j < 8; ++j)
        frag[j] = f2bf(Wh[(size_t)(k0 + j) * 8192 + n]);
    ((u16x8*)whp)[chunk] = frag;

    if (chunk < 32768) ((u32x4*)hbufs)[chunk] = (u32x4){0, 0, 0, 0};   // buf0: h(0)=0
    if (chunk < 2048) bar[chunk] = 0u;                                 // barrier words
}

// Contention-free monotonic tree barrier (phase = t+1, never reset). As R1.
__device__ __forceinline__ void grid_barrier(unsigned int* bar, unsigned int phase,
                                             bool do_inv, int W) {
    __syncthreads();   // drain h stores to the coherence point
    if (threadIdx.x < 64) {
        const int lane = threadIdx.x;
        if (lane == 0) astore(&bar[W], phase);                 // arrival
        if (W < 8) {
            unsigned int* sl = &bar[W * 32 + (lane & 31)];
            while (!__all((int)(aload(sl) >= phase)))
                __builtin_amdgcn_s_sleep(1);
            if (lane == 0) astore(&bar[512 + 16 * W], phase);  // done[W]
            if (W == 0) {
                unsigned int* dn = &bar[512 + 16 * (lane & 7)];
                while (!__all((int)(aload(dn) >= phase)))
                    __builtin_amdgcn_s_sleep(1);
                if (lane < 32) astore(&bar[1024 + 16 * lane], phase);  // broadcast
            }
        }
        if (lane == 0 && W != 0) {
            unsigned int* rl = &bar[1024 + 16 * (W & 31)];
            while (aload(rl) < phase)
                __builtin_amdgcn_s_sleep(1);
        }
        if (do_inv)
            __builtin_amdgcn_fence(__ATOMIC_ACQUIRE, "agent");   // buffer_inv (L1+L2)
    }
    __syncthreads();
}

__global__ __launch_bounds__(WG_THREADS, 2) void lstm_persist(
    const float* __restrict__ x,  const float* __restrict__ Wx,
    const float* __restrict__ b,  const float* __restrict__ Wph,
    const float* __restrict__ bp, const unsigned short* __restrict__ whp,
    unsigned short* hbufs, float* hfin,
    unsigned int* bar, float* out)
{
    extern __shared__ char lds[];
    const int tid = threadIdx.x;
    const int W   = blockIdx.x;

    // stage this WG's Wh slice (128 KB) into LDS (linear copy; layout matches pack)
    {
        const u32x4* src = (const u32x4*)whp + (size_t)W * 8192;
        u32x4* dst = (u32x4*)lds;
        for (int i = tid; i < 8192; i += WG_THREADS) dst[i] = src[i];
    }
    unsigned short* hstage = (unsigned short*)(lds + HSTAGE_OFF);   // [row][u] bf16, 2 KB
    __syncthreads();

    const int lane = tid & 63;
    const int wv   = tid >> 6;
    const int wv2  = wv & 3;            // M-tile: rows 32*wv2 .. +31
    const int kh   = wv >> 2;           // K-half: k in [kh*1024, kh*1024+1024)
    const int l31  = lane & 31;
    const int oct  = lane >> 5;         // k-octet within fragment
    const int u    = lane & 7;          // hidden unit within slice
    const int gamma= (lane >> 3) & 3;   // gate index of this lane's column

    // gate-wise Wx/bias scalars for this lane's unit (INPUT_DIM = 1)
    const int nbase = W * 8 + u;
    float wxg[4], bbg[4];
    #pragma unroll
    for (int g = 0; g < 4; ++g) {
        wxg[g] = Wx[g * 2048 + nbase];
        bbg[g] = b[g * 2048 + nbase];
    }

    // A-fragment (32x32x16): row = lane&31 (within M-tile), k-octet = oct.
    // h layout h[kblk][row][8] (identical buffer layout to R1): x8-index =
    // (kh*128 + kt*2 + oct)*128 + 32*wv2 + (lane&31); per-kt stride 256.
    const int abase = kh * 16384 + oct * 128 + 32 * wv2 + l31;
    // B-fragment LDS base: (kh*64 + kt)*1024 + lane*16 bytes
    const char* lpB0 = lds + kh * 65536 + lane * 16;

    char* redp = lds + RED_OFF + (size_t)(wv2 * 64 + lane) * RED_STRIDE;

    const int g0 = gamma & 1, g1 = (gamma >> 1) & 1;
    float c_state[4] = {0.f, 0.f, 0.f, 0.f};   // meaningful on kh==0 waves

    for (int t = 0; t < STEPS; ++t) {
        unsigned short* hcur  = hbufs + (size_t)(t & 3) * 262144;        // elements
        unsigned short* hnext = hbufs + (size_t)((t + 1) & 3) * 262144;
        const bf16x8* hc8 = (const bf16x8*)hcur;

        // xv preload (only consumer waves need it); hidden under the k-loop
        float xva[4];
        if (kh == 0) {
            #pragma unroll
            for (int a = 0; a < 4; ++a) {
                int row = 32 * wv2 + gamma + 8 * a + 4 * oct;
                xva[a] = x[row * SEQ_LEN + t];
            }
        }

        // 16-deep rotating register prefetch of A fragments
        bf16x8 a_pf[PF];
        #pragma unroll
        for (int i = 0; i < PF; ++i)
            a_pf[i] = hc8[abase + i * 256];

        f32x16 acc = {0.f};
        // phase A (kt 0..47): prefetch kt+PF always valid (tail-split, R8)
        #pragma unroll 16
        for (int kt = 0; kt < KTILES - PF; ++kt) {
            bf16x8 a_cur = a_pf[kt & (PF - 1)];
            a_pf[kt & (PF - 1)] = hc8[abase + (kt + PF) * 256];
            bf16x8 bb = *(const bf16x8*)(lpB0 + kt * 1024);
            acc = __builtin_amdgcn_mfma_f32_32x32x16_bf16(a_cur, bb, acc, 0, 0, 0);
        }
        // phase B (kt 48..63): consume a_pf, no prefetch
        #pragma unroll
        for (int i = 0; i < PF; ++i) {
            bf16x8 bb = *(const bf16x8*)(lpB0 + ((KTILES - PF) + i) * 1024);
            acc = __builtin_amdgcn_mfma_f32_32x32x16_bf16(a_pf[i], bb, acc, 0, 0, 0);
        }

        // ---- K-half reduction through LDS (kh=1 writes, kh=0 adds) ----
        if (kh == 1) {
            #pragma unroll
            for (int j = 0; j < 8; ++j) {
                float2 v; v.x = acc[2 * j]; v.y = acc[2 * j + 1];
                *(float2*)(redp + 8 * j) = v;
            }
        }
        __syncthreads();

        const bool last = (t == STEPS - 1);
        if (kh == 0) {
            #pragma unroll
            for (int j = 0; j < 8; ++j) {
                float2 v = *(const float2*)(redp + 8 * j);
                acc[2 * j] += v.x; acc[2 * j + 1] += v.y;
            }
            // C/D layout: col = lane&31, row = (reg&3) + 8*(reg>>2) + 4*oct.
            // xor-gather: lane gamma of each 8-group finishes reg 4a+gamma,
            // so all 64 lanes do gate math (3 shuffles + selects per quad).
            #pragma unroll
            for (int a = 0; a < 4; ++a) {
                float q0 = acc[4 * a + 0], q1 = acc[4 * a + 1];
                float q2 = acc[4 * a + 2], q3 = acc[4 * a + 3];
                float s1  = g0 ? (g1 ? q2 : q0) : (g1 ? q3 : q1);   // acc[4a+(γ^1)]
                float s2  = g1 ? (g0 ? q1 : q0) : (g0 ? q3 : q2);   // acc[4a+(γ^2)]
                float s3  = g1 ? (g0 ? q0 : q1) : (g0 ? q2 : q3);   // acc[4a+(γ^3)]
                float own = g1 ? (g0 ? q3 : q2) : (g0 ? q1 : q0);   // acc[4a+γ]
                float r1 = __shfl_xor(s1, 8, 64);
                float r2 = __shfl_xor(s2, 16, 64);
                float r3 = __shfl_xor(s3, 24, 64);
                float zg = g1 ? (g0 ? r3 : r2) : (g0 ? r1 : own);
                float zi = g1 ? (g0 ? r2 : r3) : (g0 ? own : r1);
                float zf = g1 ? (g0 ? r1 : own) : (g0 ? r3 : r2);
                float zo = g1 ? (g0 ? own : r1) : (g0 ? r2 : r3);
                zg += xva[a] * wxg[0] + bbg[0];
                zi += xva[a] * wxg[1] + bbg[1];
                zf += xva[a] * wxg[2] + bbg[2];
                zo += xva[a] * wxg[3] + bbg[3];
                float cn = tanh_f(zg) * sigm(zi) + c_state[a] * sigm(zf);
                c_state[a] = cn;
                float h = tanh_f(cn) * sigm(zo);
                int row = 32 * wv2 + gamma + 8 * a + 4 * oct;
                hstage[row * 8 + u] = f2bf(h);
                if (last)
                    __hip_atomic_store(&hfin[row * HIDDEN + W * 8 + u], h,
                                       __ATOMIC_RELAXED, __HIP_MEMORY_SCOPE_AGENT);
            }
        }
        __syncthreads();   // hstage complete (and red-area reuse fenced)
        // cooperative coalesced write of this WG's 2 KB h-block (1 dword/thread;
        // lane-contiguous posted stores -> full-line write-through)
        astore(&((unsigned int*)hnext)[W * 512 + tid],
               ((const unsigned int*)hstage)[tid]);
        // inv every 4th barrier (stale L2 age <= 4 with the 4-buffer rotation);
        // t==254 (phase 2) also covers the hfin handoff to the cached epilogue.
        grid_barrier(bar, (unsigned int)(t + 1), (t & 3) == 2 || last, W);
    }

    // ---- classifier + softmax epilogue: WG b handles batch row b ----
    if (W < BATCH) {
        float part[CLASSES];
        #pragma unroll
        for (int c = 0; c < CLASSES; ++c) part[c] = 0.f;
        for (int k = tid; k < HIDDEN; k += WG_THREADS) {
            float hv = hfin[W * HIDDEN + k];
            #pragma unroll
            for (int c = 0; c < CLASSES; ++c) part[c] += hv * Wph[k * CLASSES + c];
        }
        #pragma unroll
        for (int c = 0; c < CLASSES; ++c)
            for (int off = 32; off > 0; off >>= 1)
                part[c] += __shfl_xor(part[c], off, 64);
        float* red = (float*)(lds + LDS_WH);
        __syncthreads();
        const int wvq = tid >> 6;
        if ((tid & 63) == 0)
            for (int c = 0; c < CLASSES; ++c) red[wvq * CLASSES + c] = part[c];
        __syncthreads();
        if (tid == 0) {
            float lg[CLASSES];
            for (int c = 0; c < CLASSES; ++c) {
                float sm = bp[c];
                for (int w8 = 0; w8 < 8; ++w8) sm += red[w8 * CLASSES + c];
                lg[c] = sm;
            }
            float mx = lg[0];
            for (int c = 1; c < CLASSES; ++c) mx = fmaxf(mx, lg[c]);
            float se = 0.f;
            for (int c = 0; c < CLASSES; ++c) { lg[c] = __expf(lg[c] - mx); se += lg[c]; }
            float inv = 1.0f / se;
            for (int c = 0; c < CLASSES; ++c) out[W * CLASSES + c] = lg[c] * inv;
        }
    }
}

extern "C" void kernel_launch(void* const* d_in, const int* in_sizes, int n_in,
                              void* d_out, int out_size, void* d_ws, size_t ws_size,
                              hipStream_t stream) {
    const float* x   = (const float*)d_in[0];
    const float* Wx  = (const float*)d_in[1];
    const float* Wh  = (const float*)d_in[2];
    const float* b   = (const float*)d_in[3];
    const float* Wph = (const float*)d_in[4];
    const float* bp  = (const float*)d_in[5];
    float* out = (float*)d_out;

    char* ws = (char*)d_ws;
    unsigned short* whp  = (unsigned short*)(ws + WHP_OFF);
    unsigned short* hbufs= (unsigned short*)(ws + HB_OFF);
    float*          hfin = (float*)(ws + HF_OFF);
    unsigned int*   bar  = (unsigned int*)(ws + BAR_OFF);

    hipFuncSetAttribute((const void*)lstm_persist,
                        hipFuncAttributeMaxDynamicSharedMemorySize, LDS_ALL);

    lstm_pack_kernel<<<8192, 256, 0, stream>>>(Wh, whp, hbufs, bar);
    lstm_persist<<<NWG, WG_THREADS, LDS_ALL, stream>>>(x, Wx, b, Wph, bp,
                                                       whp, hbufs, hfin, bar, out);
}

// Round 10
// 2418.478 us; speedup vs baseline: 1.6244x; 1.0097x over previous
//
#include <hip/hip_runtime.h>
#include <hip/hip_bf16.h>

#define SEQ_LEN 256
#define HIDDEN  2048
#define CLASSES 10
#define BATCH   128
#define NWG     256
#define WG_THREADS 512
#define STEPS   (SEQ_LEN - 1)
#define KTILES  64            // per K-half: 1024 / 16
#define PF      16            // A-prefetch depth (ktiles ahead)
#define LDS_WH  131072
#define RED_OFF    LDS_WH                  // K-half reduction: 256 slots * 72 B
#define RED_STRIDE 72
#define LDS_ALL    (LDS_WH + 18432)

typedef __attribute__((ext_vector_type(8)))  short  bf16x8;
typedef __attribute__((ext_vector_type(8)))  unsigned short u16x8;
typedef __attribute__((ext_vector_type(16))) float  f32x16;
typedef __attribute__((ext_vector_type(4)))  unsigned int u32x4;

// ---- workspace layout (bytes) ----
#define WHP_OFF  0
#define HB_OFF   33554432UL                    // 4 x 512 KB rotating h buffers, layout h[kblk][row][u]
#define HF_OFF   (HB_OFF + 4UL * 524288UL)     // fp32 h_final [128][2048]
#define BAR_OFF  (HF_OFF + 1048576UL)
// bar layout (dwords): as R1 (contention-free tree, monotonic phases).
// Session lessons: R2 flat all-poll barrier = coherence-point contention.
// R4: don't perturb the MFMA/load schedule for ILP. R5: agent-scope partial
// exchange = HBM write-through + partial-line amplification; only
// lane-contiguous stores merge into full lines. R6: all-to-all consumption ->
// flags can't beat the barrier. R7: 128-VGPR breg = spills. R8: tail-split
// ~4% win. R9: 32x32 MFMA + K-half split halved LDS B-reads -> time FLAT
// (LDS not binding; VALUBusy 23.6->16.2 with no dur change). Binding terms:
// TCP A-stream (~3.4us/CU/step floor), barrier (~2us), step-tail serial.
// R10: direct coalesced h-write — under the 32x32 lane map, each (a) store
// covers exactly 2 full 64B lines (lane=oct*32+gamma*8+u -> byte
// (gamma+4oct)*16+u*2) so hstage LDS staging + syncthreads + 2KB copy are
// deleted; stores issue early inside the gate loop and drain under the
// barrier's first syncthreads.

__device__ __forceinline__ unsigned short f2bf(float f) {
    unsigned int u = __float_as_uint(f);
    return (unsigned short)((u + 0x7FFFu + ((u >> 16) & 1u)) >> 16);
}
__device__ __forceinline__ float sigm(float z)  { return 1.0f / (1.0f + __expf(-z)); }
__device__ __forceinline__ float tanh_f(float z){ return 2.0f / (1.0f + __expf(-2.0f * z)) - 1.0f; }

__device__ __forceinline__ unsigned int aload(const unsigned int* p) {
    return __hip_atomic_load(p, __ATOMIC_RELAXED, __HIP_MEMORY_SCOPE_AGENT);
}
__device__ __forceinline__ void astore(unsigned int* p, unsigned int v) {
    __hip_atomic_store(p, v, __ATOMIC_RELAXED, __HIP_MEMORY_SCOPE_AGENT);
}
__device__ __forceinline__ void astore_s(unsigned short* p, unsigned short v) {
    __hip_atomic_store(p, v, __ATOMIC_RELAXED, __HIP_MEMORY_SCOPE_AGENT);
}

// Pack Wh [2048][8192] fp32 -> bf16 32x32x16 B-fragments.
// whp chunk = W*8192 + kh*4096 + kt*64 + lane (16 B units).
// Fragment: col = lane&31 -> (gate = col>>3, u = col&7), k = kh*1024 + kt*16
// + (lane>>5)*8 + j.  (k-octet convention cancels between A and B.)
__global__ void lstm_pack_kernel(const float* __restrict__ Wh,
                                 unsigned short* __restrict__ whp,
                                 unsigned short* __restrict__ hbufs,
                                 unsigned int* __restrict__ bar) {
    int chunk = blockIdx.x * 256 + threadIdx.x;     // 2,097,152 chunks total
    int lane = chunk & 63;
    int kt   = (chunk >> 6) & 63;
    int kh   = (chunk >> 12) & 1;
    int W    = chunk >> 13;
    int c    = lane & 31;
    int oct  = lane >> 5;
    int gate = c >> 3, u = c & 7;
    int n    = gate * 2048 + W * 8 + u;
    int k0   = kh * 1024 + kt * 16 + oct * 8;
    u16x8 frag;
    #pragma unroll
    for (int j = 0; j < 8; ++j)
        frag[j] = f2bf(Wh[(size_t)(k0 + j) * 8192 + n]);
    ((u16x8*)whp)[chunk] = frag;

    if (chunk < 32768) ((u32x4*)hbufs)[chunk] = (u32x4){0, 0, 0, 0};   // buf0: h(0)=0
    if (chunk < 2048) bar[chunk] = 0u;                                 // barrier words
}

// Contention-free monotonic tree barrier (phase = t+1, never reset). As R1.
__device__ __forceinline__ void grid_barrier(unsigned int* bar, unsigned int phase,
                                             bool do_inv, int W) {
    __syncthreads();   // drain h stores to the coherence point
    if (threadIdx.x < 64) {
        const int lane = threadIdx.x;
        if (lane == 0) astore(&bar[W], phase);                 // arrival
        if (W < 8) {
            unsigned int* sl = &bar[W * 32 + (lane & 31)];
            while (!__all((int)(aload(sl) >= phase)))
                __builtin_amdgcn_s_sleep(1);
            if (lane == 0) astore(&bar[512 + 16 * W], phase);  // done[W]
            if (W == 0) {
                unsigned int* dn = &bar[512 + 16 * (lane & 7)];
                while (!__all((int)(aload(dn) >= phase)))
                    __builtin_amdgcn_s_sleep(1);
                if (lane < 32) astore(&bar[1024 + 16 * lane], phase);  // broadcast
            }
        }
        if (lane == 0 && W != 0) {
            unsigned int* rl = &bar[1024 + 16 * (W & 31)];
            while (aload(rl) < phase)
                __builtin_amdgcn_s_sleep(1);
        }
        if (do_inv)
            __builtin_amdgcn_fence(__ATOMIC_ACQUIRE, "agent");   // buffer_inv (L1+L2)
    }
    __syncthreads();
}

__global__ __launch_bounds__(WG_THREADS, 2) void lstm_persist(
    const float* __restrict__ x,  const float* __restrict__ Wx,
    const float* __restrict__ b,  const float* __restrict__ Wph,
    const float* __restrict__ bp, const unsigned short* __restrict__ whp,
    unsigned short* hbufs, float* hfin,
    unsigned int* bar, float* out)
{
    extern __shared__ char lds[];
    const int tid = threadIdx.x;
    const int W   = blockIdx.x;

    // stage this WG's Wh slice (128 KB) into LDS (linear copy; layout matches pack)
    {
        const u32x4* src = (const u32x4*)whp + (size_t)W * 8192;
        u32x4* dst = (u32x4*)lds;
        for (int i = tid; i < 8192; i += WG_THREADS) dst[i] = src[i];
    }
    __syncthreads();

    const int lane = tid & 63;
    const int wv   = tid >> 6;
    const int wv2  = wv & 3;            // M-tile: rows 32*wv2 .. +31
    const int kh   = wv >> 2;           // K-half: k in [kh*1024, kh*1024+1024)
    const int l31  = lane & 31;
    const int oct  = lane >> 5;         // k-octet within fragment
    const int u    = lane & 7;          // hidden unit within slice
    const int gamma= (lane >> 3) & 3;   // gate index of this lane's column

    // gate-wise Wx/bias scalars for this lane's unit (INPUT_DIM = 1)
    const int nbase = W * 8 + u;
    float wxg[4], bbg[4];
    #pragma unroll
    for (int g = 0; g < 4; ++g) {
        wxg[g] = Wx[g * 2048 + nbase];
        bbg[g] = b[g * 2048 + nbase];
    }

    // A-fragment (32x32x16): row = lane&31 (within M-tile), k-octet = oct.
    // h layout h[kblk][row][8] (identical buffer layout to R1): x8-index =
    // (kh*128 + kt*2 + oct)*128 + 32*wv2 + (lane&31); per-kt stride 256.
    const int abase = kh * 16384 + oct * 128 + 32 * wv2 + l31;
    // B-fragment LDS base: (kh*64 + kt)*1024 + lane*16 bytes
    const char* lpB0 = lds + kh * 65536 + lane * 16;

    char* redp = lds + RED_OFF + (size_t)(wv2 * 64 + lane) * RED_STRIDE;

    const int g0 = gamma & 1, g1 = (gamma >> 1) & 1;
    float c_state[4] = {0.f, 0.f, 0.f, 0.f};   // meaningful on kh==0 waves

    for (int t = 0; t < STEPS; ++t) {
        unsigned short* hcur  = hbufs + (size_t)(t & 3) * 262144;        // elements
        unsigned short* hnext = hbufs + (size_t)((t + 1) & 3) * 262144;
        const bf16x8* hc8 = (const bf16x8*)hcur;

        // xv preload (only consumer waves need it)
        float xva[4];
        if (kh == 0) {
            #pragma unroll
            for (int a = 0; a < 4; ++a) {
                int row = 32 * wv2 + gamma + 8 * a + 4 * oct;
                xva[a] = x[row * SEQ_LEN + t];
            }
        }

        // 16-deep rotating register prefetch of A fragments
        bf16x8 a_pf[PF];
        #pragma unroll
        for (int i = 0; i < PF; ++i)
            a_pf[i] = hc8[abase + i * 256];

        f32x16 acc = {0.f};
        // phase A (kt 0..47): prefetch kt+PF always valid (tail-split, R8)
        #pragma unroll 16
        for (int kt = 0; kt < KTILES - PF; ++kt) {
            bf16x8 a_cur = a_pf[kt & (PF - 1)];
            a_pf[kt & (PF - 1)] = hc8[abase + (kt + PF) * 256];
            bf16x8 bb = *(const bf16x8*)(lpB0 + kt * 1024);
            acc = __builtin_amdgcn_mfma_f32_32x32x16_bf16(a_cur, bb, acc, 0, 0, 0);
        }
        // phase B (kt 48..63): consume a_pf, no prefetch
        #pragma unroll
        for (int i = 0; i < PF; ++i) {
            bf16x8 bb = *(const bf16x8*)(lpB0 + ((KTILES - PF) + i) * 1024);
            acc = __builtin_amdgcn_mfma_f32_32x32x16_bf16(a_pf[i], bb, acc, 0, 0, 0);
        }

        // ---- K-half reduction through LDS (kh=1 writes, kh=0 adds) ----
        if (kh == 1) {
            #pragma unroll
            for (int j = 0; j < 8; ++j) {
                float2 v; v.x = acc[2 * j]; v.y = acc[2 * j + 1];
                *(float2*)(redp + 8 * j) = v;
            }
        }
        __syncthreads();

        const bool last = (t == STEPS - 1);
        if (kh == 0) {
            #pragma unroll
            for (int j = 0; j < 8; ++j) {
                float2 v = *(const float2*)(redp + 8 * j);
                acc[2 * j] += v.x; acc[2 * j + 1] += v.y;
            }
            // C/D layout: col = lane&31, row = (reg&3) + 8*(reg>>2) + 4*oct.
            // xor-gather: lane gamma of each 8-group finishes reg 4a+gamma,
            // so all 64 lanes do gate math (3 shuffles + selects per quad).
            #pragma unroll
            for (int a = 0; a < 4; ++a) {
                float q0 = acc[4 * a + 0], q1 = acc[4 * a + 1];
                float q2 = acc[4 * a + 2], q3 = acc[4 * a + 3];
                float s1  = g0 ? (g1 ? q2 : q0) : (g1 ? q3 : q1);   // acc[4a+(γ^1)]
                float s2  = g1 ? (g0 ? q1 : q0) : (g0 ? q3 : q2);   // acc[4a+(γ^2)]
                float s3  = g1 ? (g0 ? q0 : q1) : (g0 ? q2 : q3);   // acc[4a+(γ^3)]
                float own = g1 ? (g0 ? q3 : q2) : (g0 ? q1 : q0);   // acc[4a+γ]
                float r1 = __shfl_xor(s1, 8, 64);
                float r2 = __shfl_xor(s2, 16, 64);
                float r3 = __shfl_xor(s3, 24, 64);
                float zg = g1 ? (g0 ? r3 : r2) : (g0 ? r1 : own);
                float zi = g1 ? (g0 ? r2 : r3) : (g0 ? own : r1);
                float zf = g1 ? (g0 ? r1 : own) : (g0 ? r3 : r2);
                float zo = g1 ? (g0 ? own : r1) : (g0 ? r2 : r3);
                zg += xva[a] * wxg[0] + bbg[0];
                zi += xva[a] * wxg[1] + bbg[1];
                zf += xva[a] * wxg[2] + bbg[2];
                zo += xva[a] * wxg[3] + bbg[3];
                float cn = tanh_f(zg) * sigm(zi) + c_state[a] * sigm(zf);
                c_state[a] = cn;
                float h = tanh_f(cn) * sigm(zo);
                int row = 32 * wv2 + gamma + 8 * a + 4 * oct;
                // direct coalesced h-write: for fixed a, the wave's 64 lanes
                // cover bytes (gamma+4*oct)*16 + u*2 + 128*a + 512*wv2 of the
                // W-block = 2 full 64B lines per store instruction (R5-safe).
                astore_s(&hnext[W * 1024 + row * 8 + u], f2bf(h));
                if (last)
                    __hip_atomic_store(&hfin[row * HIDDEN + W * 8 + u], h,
                                       __ATOMIC_RELAXED, __HIP_MEMORY_SCOPE_AGENT);
            }
        }
        // no hstage staging / copy: stores above drain under the barrier's
        // first __syncthreads (s_waitcnt vmcnt(0) in every wave), then arrival.
        // inv every 4th barrier (stale L2 age <= 4 with the 4-buffer rotation);
        // t==254 (phase 2) also covers the hfin handoff to the cached epilogue.
        grid_barrier(bar, (unsigned int)(t + 1), (t & 3) == 2 || last, W);
    }

    // ---- classifier + softmax epilogue: WG b handles batch row b ----
    if (W < BATCH) {
        float part[CLASSES];
        #pragma unroll
        for (int c = 0; c < CLASSES; ++c) part[c] = 0.f;
        for (int k = tid; k < HIDDEN; k += WG_THREADS) {
            float hv = hfin[W * HIDDEN + k];
            #pragma unroll
            for (int c = 0; c < CLASSES; ++c) part[c] += hv * Wph[k * CLASSES + c];
        }
        #pragma unroll
        for (int c = 0; c < CLASSES; ++c)
            for (int off = 32; off > 0; off >>= 1)
                part[c] += __shfl_xor(part[c], off, 64);
        float* red = (float*)(lds + RED_OFF);
        __syncthreads();
        const int wvq = tid >> 6;
        if ((tid & 63) == 0)
            for (int c = 0; c < CLASSES; ++c) red[wvq * CLASSES + c] = part[c];
        __syncthreads();
        if (tid == 0) {
            float lg[CLASSES];
            for (int c = 0; c < CLASSES; ++c) {
                float sm = bp[c];
                for (int w8 = 0; w8 < 8; ++w8) sm += red[w8 * CLASSES + c];
                lg[c] = sm;
            }
            float mx = lg[0];
            for (int c = 1; c < CLASSES; ++c) mx = fmaxf(mx, lg[c]);
            float se = 0.f;
            for (int c = 0; c < CLASSES; ++c) { lg[c] = __expf(lg[c] - mx); se += lg[c]; }
            float inv = 1.0f / se;
            for (int c = 0; c < CLASSES; ++c) out[W * CLASSES + c] = lg[c] * inv;
        }
    }
}

extern "C" void kernel_launch(void* const* d_in, const int* in_sizes, int n_in,
                              void* d_out, int out_size, void* d_ws, size_t ws_size,
                              hipStream_t stream) {
    const float* x   = (const float*)d_in[0];
    const float* Wx  = (const float*)d_in[1];
    const float* Wh  = (const float*)d_in[2];
    const float* b   = (const float*)d_in[3];
    const float* Wph = (const float*)d_in[4];
    const float* bp  = (const float*)d_in[5];
    float* out = (float*)d_out;

    char* ws = (char*)d_ws;
    unsigned short* whp  = (unsigned short*)(ws + WHP_OFF);
    unsigned short* hbufs= (unsigned short*)(ws + HB_OFF);
    float*          hfin = (float*)(ws + HF_OFF);
    unsigned int*   bar  = (unsigned int*)(ws + BAR_OFF);

    hipFuncSetAttribute((const void*)lstm_persist,
                        hipFuncAttributeMaxDynamicSharedMemorySize, LDS_ALL);

    lstm_pack_kernel<<<8192, 256, 0, stream>>>(Wh, whp, hbufs, bar);
    lstm_persist<<<NWG, WG_THREADS, LDS_ALL, stream>>>(x, Wx, b, Wph, bp,
                                                       whp, hbufs, hfin, bar, out);
}